// Round 1
// baseline (1074.468 us; speedup 1.0000x reference)
//
#include <hip/hip_runtime.h>

// Problem dims
#define VV 100000
#define EE 256
#define HH 256
#define BB 16
#define SS 64
#define NEGV -1e9f

// workspace layout (float offsets)
#define OFF_X1   0               // B*S*4H = 1048576
#define OFF_XX   1048576         // 1048576
#define OFF_A    2097152         // 262144  (Aemb, then A)
#define OFF_SH   2359296         // 262144  (shared LSTM outputs)
#define OFF_SWM  2621440         // 1048576 (shared @ Wm^T)
#define OFF_HSH  3670016         // 8192 (double-buffered shared-lstm h)
#define OFF_HTA  3678208         // 4096 (task h)
#define OFF_HW   3682304         // 4096
#define OFF_SI   3686400         // 1024
#define OFF_BAR  3687424         // 1024 uints (32 groups x 32 stride)

__device__ __forceinline__ float sigf(float x) { return 1.f / (1.f + __expf(-x)); }

__device__ __forceinline__ float gload(const float* p) {
  return __hip_atomic_load(p, __ATOMIC_RELAXED, __HIP_MEMORY_SCOPE_AGENT);
}
__device__ __forceinline__ void gstore(float* p, float v) {
  __hip_atomic_store(p, v, __ATOMIC_RELAXED, __HIP_MEMORY_SCOPE_AGENT);
}

// monotonic-epoch group barrier; counter zeroed by K1 each launch
__device__ __forceinline__ void group_barrier(unsigned* ctr, unsigned target) {
  __syncthreads();  // compiler drains vmcnt/lgkmcnt before s_barrier
  if (threadIdx.x == 0) {
    asm volatile("s_waitcnt vmcnt(0) lgkmcnt(0)" ::: "memory");
    __hip_atomic_fetch_add(ctr, 1u, __ATOMIC_RELAXED, __HIP_MEMORY_SCOPE_AGENT);
    while (__hip_atomic_load(ctr, __ATOMIC_RELAXED, __HIP_MEMORY_SCOPE_AGENT) < target) {
      __builtin_amdgcn_s_sleep(1);
    }
  }
  __syncthreads();
}

// 16-row x 128-col output tile GEMM helper, K=256. eL: [16][260], wL: [128][68]
__device__ __forceinline__ void tile_mm(const float* __restrict__ W, int ldw, int wcol0,
                                        int j0, const float* eL, float* wL, float acc[8]) {
  const int i = threadIdx.x >> 4, jj = threadIdx.x & 15;
  for (int kc = 0; kc < 4; ++kc) {
    __syncthreads();
    const int k0 = kc * 64;
    #pragma unroll
    for (int m = 0; m < 32; ++m) {
      int v = threadIdx.x + (m << 8);
      int row = v >> 6, col = v & 63;
      wL[row * 68 + col] = W[(j0 + row) * ldw + wcol0 + k0 + col];
    }
    __syncthreads();
    const float* ebase = eL + i * 260 + k0;
    #pragma unroll 4
    for (int k4 = 0; k4 < 16; ++k4) {
      float4 e4 = *(const float4*)(ebase + k4 * 4);
      #pragma unroll
      for (int u = 0; u < 8; ++u) {
        float4 w4 = *(const float4*)(wL + (jj + (u << 4)) * 68 + k4 * 4);
        acc[u] += e4.x * w4.x + e4.y * w4.y + e4.z * w4.z + e4.w * w4.w;
      }
    }
  }
}

// K1: emb gather + X1 = emb@W_ih^T + (b_ih+b_hh); Xx = emb@Wx^T + b_cell;
//     Aemb = emb@Ws3^T + Ws_b. Also zero-inits h buffers + barrier counters.
__global__ __launch_bounds__(256) void k1_precompute(
    const int* __restrict__ x, const float* __restrict__ embed,
    const float* __restrict__ W_ih, const float* __restrict__ b_ih,
    const float* __restrict__ b_hh, const float* __restrict__ Ws_w,
    const float* __restrict__ Ws_b, const float* __restrict__ Wx,
    const float* __restrict__ b_cell, float* __restrict__ ws) {
  __shared__ float eL[16 * 260];
  __shared__ float wL[128 * 68];
  const int rt = blockIdx.x / 18, jb = blockIdx.x % 18;
  if (blockIdx.x == 0) {
    for (int i = threadIdx.x; i < 8192 + 4096; i += 256) ws[OFF_HSH + i] = 0.f;
    unsigned* bar = (unsigned*)(ws + OFF_BAR);
    for (int i = threadIdx.x; i < 1024; i += 256) bar[i] = 0u;
  }
  for (int i = 0; i < 16; ++i) {
    int xi = x[rt * 16 + i];
    eL[i * 260 + threadIdx.x] = embed[xi * 256 + threadIdx.x];
  }
  const float* W; const float* bias1; const float* bias2 = nullptr;
  int ldw, wcol0, j0, ostride; float* out;
  if (jb < 8)       { W = W_ih; ldw = 256; wcol0 = 0;   j0 = jb * 128;        out = ws + OFF_X1; ostride = 1024; bias1 = b_ih; bias2 = b_hh; }
  else if (jb < 16) { W = Wx;   ldw = 256; wcol0 = 0;   j0 = (jb - 8) * 128;  out = ws + OFF_XX; ostride = 1024; bias1 = b_cell; }
  else              { W = Ws_w; ldw = 768; wcol0 = 512; j0 = (jb - 16) * 128; out = ws + OFF_A;  ostride = 256;  bias1 = Ws_b; }
  float acc[8];
  #pragma unroll
  for (int u = 0; u < 8; ++u) acc[u] = 0.f;
  tile_mm(W, ldw, wcol0, j0, eL, wL, acc);
  const int i = threadIdx.x >> 4, jj = threadIdx.x & 15;
  const int r = rt * 16 + i;
  #pragma unroll
  for (int u = 0; u < 8; ++u) {
    int j = j0 + jj + (u << 4);
    float bv = bias1[j] + (bias2 ? bias2[j] : 0.f);
    out[r * ostride + j] = acc[u] + bv;
  }
}

// K2: shared LSTM, 64 steps. grid 128 = 16 batches x 8 slices (32 hidden each).
__global__ __launch_bounds__(256) void k2_shared_lstm(
    const float* __restrict__ W_hh, float* __restrict__ ws) {
  const int b = blockIdx.x & 15, o = blockIdx.x >> 4;
  unsigned* bar = (unsigned*)(ws + OFF_BAR) + b * 32;
  __shared__ float hL[256];
  __shared__ float gA[128];
  __shared__ float cA[32];
  const int t = threadIdx.x;
  if (t < 32) cA[t] = 0.f;
  float* hsh = ws + OFF_HSH;
  const float* X1 = ws + OFF_X1;
  float* sh = ws + OFF_SH;
  const int row_l = t >> 1, half = t & 1;
  const int gate = row_l >> 5, nn = row_l & 31;
  const int grow = gate * 256 + o * 32 + nn;
  const float* wrow = W_hh + grow * 256 + half * 128;
  unsigned epoch = 0;
  for (int st = 0; st < 64; ++st) {
    const int cur = st & 1;
    hL[t] = gload(hsh + cur * 4096 + b * 256 + t);
    __syncthreads();
    const float* hp = &hL[half * 128];
    float p = 0.f;
    #pragma unroll 8
    for (int k = 0; k < 128; k += 4) {
      float4 h4 = *(const float4*)(hp + k);
      float4 w4 = *(const float4*)(wrow + k);
      p += h4.x * w4.x + h4.y * w4.y + h4.z * w4.z + h4.w * w4.w;
    }
    p += __shfl_xor(p, 1);
    if (half == 0) gA[row_l] = p + X1[(b * 64 + st) * 1024 + grow];
    __syncthreads();
    if (t < 32) {
      float gi = gA[t], gf = gA[32 + t], gg = gA[64 + t], go = gA[96 + t];
      float c = sigf(gf) * cA[t] + sigf(gi) * tanhf(gg);
      cA[t] = c;
      float hn = sigf(go) * tanhf(c);
      int n = o * 32 + t;
      gstore(hsh + (cur ^ 1) * 4096 + b * 256 + n, hn);
      sh[(b * 64 + st) * 256 + n] = hn;
    }
    ++epoch;
    group_barrier(bar, 8u * epoch);
  }
}

// K3: A += shared@Ws1^T ; SWm = shared@Wm^T.
__global__ __launch_bounds__(256) void k3_precompute2(
    const float* __restrict__ Ws_w, const float* __restrict__ Wm,
    float* __restrict__ ws) {
  __shared__ float eL[16 * 260];
  __shared__ float wL[128 * 68];
  const int rt = blockIdx.x / 10, jb = blockIdx.x % 10;
  const float* sh = ws + OFF_SH;
  for (int i = 0; i < 16; ++i)
    eL[i * 260 + threadIdx.x] = sh[(rt * 16 + i) * 256 + threadIdx.x];
  const float* W; int ldw, wcol0, j0, ostride; float* out; bool addmode;
  if (jb < 8) { W = Wm;   ldw = 256; wcol0 = 0; j0 = jb * 128;       out = ws + OFF_SWM; ostride = 1024; addmode = false; }
  else        { W = Ws_w; ldw = 768; wcol0 = 0; j0 = (jb - 8) * 128; out = ws + OFF_A;   ostride = 256;  addmode = true; }
  float acc[8];
  #pragma unroll
  for (int u = 0; u < 8; ++u) acc[u] = 0.f;
  tile_mm(W, ldw, wcol0, j0, eL, wL, acc);
  const int i = threadIdx.x >> 4, jj = threadIdx.x & 15;
  const int r = rt * 16 + i;
  #pragma unroll
  for (int u = 0; u < 8; ++u) {
    int j = j0 + jj + (u << 4);
    if (addmode) out[r * ostride + j] += acc[u];
    else         out[r * ostride + j]  = acc[u];
  }
}

// K4: task LSTM with attention, 64 steps. grid 128 = 16 batches x 8 slices.
__global__ __launch_bounds__(256) void k4_task_lstm(
    const int* __restrict__ mask, const float* __restrict__ Ws_w,
    const float* __restrict__ Us_w, const float* __restrict__ Wh,
    const float* __restrict__ fc_w, const float* __restrict__ fc_b,
    float* __restrict__ ws, float* __restrict__ out) {
  const int b = blockIdx.x & 15, o = blockIdx.x >> 4;
  unsigned* bar = (unsigned*)(ws + OFF_BAR) + (16 + b) * 32;
  __shared__ float swmL[64 * 128];  // [s][local j]  32KB
  __shared__ float aL[8 * 256];     // [local s][k]   8KB
  __shared__ float usL[256];
  __shared__ float hL[256], hwL[256];
  __shared__ float gWhL[128], gA[128], attL[64], siL[64];
  __shared__ float cA[32];
  __shared__ int   mL[64];
  __shared__ float red[256];
  const int t = threadIdx.x;
  const float* A   = ws + OFF_A;
  const float* SWM = ws + OFF_SWM;
  const float* Xx  = ws + OFF_XX;
  float* hta = ws + OFF_HTA;
  float* hwg = ws + OFF_HW;
  float* sig = ws + OFF_SI;

  for (int v = t; v < 64 * 128; v += 256) {
    int s = v >> 7, r = v & 127;
    int j = (r >> 5) * 256 + o * 32 + (r & 31);
    swmL[v] = SWM[(b * 64 + s) * 1024 + j];
  }
  for (int v = t; v < 8 * 256; v += 256) {
    int sl = v >> 8;
    aL[v] = A[(b * 64 + o * 8 + sl) * 256 + (v & 255)];
  }
  usL[t] = Us_w[t];
  if (t < 64) mL[t] = mask[b * 64 + t];
  if (t < 32) cA[t] = 0.f;
  __syncthreads();

  const int row_l = t >> 1, half = t & 1;
  const int grow = (row_l >> 5) * 256 + o * 32 + (row_l & 31);
  unsigned epoch = 0;
  for (int st = 0; st < 64; ++st) {
    // ---- P1: load h; hw slice (32 rows) and gWh rows (128) ----
    hL[t] = gload(hta + b * 256 + t);
    __syncthreads();
    {
      int rl = t >> 3, lk = t & 7;
      int jrow = o * 32 + rl;
      const float* w = Ws_w + jrow * 768 + 256;  // Ws2 block
      float p = 0.f;
      #pragma unroll
      for (int k = lk * 32; k < lk * 32 + 32; k += 4) {
        float4 h4 = *(const float4*)(hL + k);
        float4 w4 = *(const float4*)(w + k);
        p += h4.x * w4.x + h4.y * w4.y + h4.z * w4.z + h4.w * w4.w;
      }
      p += __shfl_xor(p, 1); p += __shfl_xor(p, 2); p += __shfl_xor(p, 4);
      if (lk == 0) gstore(hwg + b * 256 + jrow, p);
    }
    {
      const float* w = Wh + grow * 256 + half * 128;
      const float* hp = &hL[half * 128];
      float p = 0.f;
      #pragma unroll 8
      for (int k = 0; k < 128; k += 4) {
        float4 h4 = *(const float4*)(hp + k);
        float4 w4 = *(const float4*)(w + k);
        p += h4.x * w4.x + h4.y * w4.y + h4.z * w4.z + h4.w * w4.w;
      }
      p += __shfl_xor(p, 1);
      if (half == 0) gWhL[row_l] = p + Xx[(b * 64 + st) * 1024 + grow];
    }
    ++epoch; group_barrier(bar, 8u * epoch);
    // ---- P2: Si rows ----
    hwL[t] = gload(hwg + b * 256 + t);
    __syncthreads();
    {
      int sl = t >> 5, l32 = t & 31;
      float p = 0.f;
      #pragma unroll
      for (int m = 0; m < 8; ++m) {
        int k = l32 + 32 * m;
        p += usL[k] * tanhf(aL[sl * 256 + k] + hwL[k]);
      }
      p += __shfl_xor(p, 1); p += __shfl_xor(p, 2); p += __shfl_xor(p, 4);
      p += __shfl_xor(p, 8); p += __shfl_xor(p, 16);
      if (l32 == 0) {
        int s = o * 8 + sl;
        gstore(sig + b * 64 + s, mL[s] ? p : NEGV);
      }
    }
    ++epoch; group_barrier(bar, 8u * epoch);
    // ---- P3: softmax, g, gates ----
    if (t < 64) siL[t] = gload(sig + b * 64 + t);
    __syncthreads();
    if (t < 64) {
      float v = siL[t];
      float mx = v;
      #pragma unroll
      for (int d = 1; d < 64; d <<= 1) mx = fmaxf(mx, __shfl_xor(mx, d));
      float e = __expf(v - mx);
      float ssum = e;
      #pragma unroll
      for (int d = 1; d < 64; d <<= 1) ssum += __shfl_xor(ssum, d);
      attL[t] = e / ssum;
    }
    __syncthreads();
    {
      float p = 0.f;
      #pragma unroll
      for (int s = half * 32; s < half * 32 + 32; ++s)
        p += attL[s] * swmL[s * 128 + row_l];
      p += __shfl_xor(p, 1);
      if (half == 0) gA[row_l] = p + gWhL[row_l];
    }
    __syncthreads();
    if (t < 32) {
      float gi = gA[t], gf = gA[32 + t], gg = gA[64 + t], go = gA[96 + t];
      float c = sigf(gf) * cA[t] + sigf(gi) * tanhf(gg);
      cA[t] = c;
      float hn = sigf(go) * tanhf(c);
      gstore(hta + b * 256 + o * 32 + t, hn);
    }
    ++epoch; group_barrier(bar, 8u * epoch);
  }
  // final classifier (one WG per batch)
  if (o == 0) {
    red[t] = gload(hta + b * 256 + t) * fc_w[t];
    __syncthreads();
    for (int dd = 128; dd > 0; dd >>= 1) {
      if (t < dd) red[t] += red[t + dd];
      __syncthreads();
    }
    if (t == 0) out[b] = 1.f / (1.f + __expf(-(red[0] + fc_b[0])));
  }
}

extern "C" void kernel_launch(void* const* d_in, const int* in_sizes, int n_in,
                              void* d_out, int out_size, void* d_ws, size_t ws_size,
                              hipStream_t stream) {
  const int*   x      = (const int*)d_in[0];
  const int*   mask   = (const int*)d_in[1];
  const float* embed  = (const float*)d_in[3];
  const float* W_ih   = (const float*)d_in[4];
  const float* W_hh   = (const float*)d_in[5];
  const float* b_ih   = (const float*)d_in[6];
  const float* b_hh   = (const float*)d_in[7];
  const float* Ws_w   = (const float*)d_in[8];
  const float* Ws_b   = (const float*)d_in[9];
  const float* Us_w   = (const float*)d_in[10];
  const float* Wx     = (const float*)d_in[12];
  const float* Wh     = (const float*)d_in[13];
  const float* Wm     = (const float*)d_in[14];
  const float* b_cell = (const float*)d_in[15];
  const float* fc_w   = (const float*)d_in[16];
  const float* fc_b   = (const float*)d_in[17];
  float* ws  = (float*)d_ws;
  float* out = (float*)d_out;

  k1_precompute<<<dim3(1152), dim3(256), 0, stream>>>(
      x, embed, W_ih, b_ih, b_hh, Ws_w, Ws_b, Wx, b_cell, ws);
  k2_shared_lstm<<<dim3(128), dim3(256), 0, stream>>>(W_hh, ws);
  k3_precompute2<<<dim3(640), dim3(256), 0, stream>>>(Ws_w, Wm, ws);
  k4_task_lstm<<<dim3(128), dim3(256), 0, stream>>>(
      mask, Ws_w, Us_w, Wh, fc_w, fc_b, ws, out);
}

// Round 2
// 744.562 us; speedup vs baseline: 1.4431x; 1.4431x over previous
//
#include <hip/hip_runtime.h>

#define NEGV -1e9f

// workspace layout (float offsets)
#define OFF_X1   0u               // 1048576  emb@W_ih^T + b
#define OFF_XX   1048576u         // 1048576  emb@Wx^T + b_cell
#define OFF_A    2097152u         // 262144   Ws_b + emb@Ws3^T (+ sh@Ws1^T)
#define OFF_SH   2359296u         // 262144   shared LSTM outputs
#define OFF_SWM  2621440u         // 1048576  shared@Wm^T
#define OFF_HSH  3670016u         // 8192  (2x4096 double-buffered shared h)
#define OFF_HTA  3678208u         // 8192  (2x4096 double-buffered task h)
#define OFF_BAR  3687424u         // 1024 u32 flags

__device__ __forceinline__ float sigf(float x) { return 1.f / (1.f + __expf(-x)); }
__device__ __forceinline__ float tanhfast(float x) {
  float e = __expf(2.f * x);
  return 1.f - __fdividef(2.f, e + 1.f);
}

__device__ __forceinline__ float gload(const float* p) {
  return __hip_atomic_load(p, __ATOMIC_RELAXED, __HIP_MEMORY_SCOPE_AGENT);
}
__device__ __forceinline__ void gstore(float* p, float v) {
  __hip_atomic_store(p, v, __ATOMIC_RELAXED, __HIP_MEMORY_SCOPE_AGENT);
}
__device__ __forceinline__ unsigned gloadU(const unsigned* p) {
  return __hip_atomic_load(p, __ATOMIC_RELAXED, __HIP_MEMORY_SCOPE_AGENT);
}
__device__ __forceinline__ void gstoreU(unsigned* p, unsigned v) {
  __hip_atomic_store(p, v, __ATOMIC_RELAXED, __HIP_MEMORY_SCOPE_AGENT);
}

// 16-row x 128-col output tile GEMM helper, K=256. eL: [16][260], wL: [128][68]
__device__ __forceinline__ void tile_mm(const float* __restrict__ W, int ldw, int wcol0,
                                        int j0, const float* eL, float* wL, float acc[8]) {
  const int i = threadIdx.x >> 4, jj = threadIdx.x & 15;
  for (int kc = 0; kc < 4; ++kc) {
    __syncthreads();
    const int k0 = kc * 64;
    #pragma unroll
    for (int m = 0; m < 32; ++m) {
      int v = threadIdx.x + (m << 8);
      int row = v >> 6, col = v & 63;
      wL[row * 68 + col] = W[(j0 + row) * ldw + wcol0 + k0 + col];
    }
    __syncthreads();
    const float* ebase = eL + i * 260 + k0;
    #pragma unroll 4
    for (int k4 = 0; k4 < 16; ++k4) {
      float4 e4 = *(const float4*)(ebase + k4 * 4);
      #pragma unroll
      for (int u = 0; u < 8; ++u) {
        float4 w4 = *(const float4*)(wL + (jj + (u << 4)) * 68 + k4 * 4);
        acc[u] += e4.x * w4.x + e4.y * w4.y + e4.z * w4.z + e4.w * w4.w;
      }
    }
  }
}

// K1: emb gather + X1 = emb@W_ih^T + (b_ih+b_hh); Xx = emb@Wx^T + b_cell;
//     A = emb@Ws3^T + Ws_b. Also zero-inits h buffers + flags.
__global__ __launch_bounds__(256) void k1_precompute(
    const int* __restrict__ x, const float* __restrict__ embed,
    const float* __restrict__ W_ih, const float* __restrict__ b_ih,
    const float* __restrict__ b_hh, const float* __restrict__ Ws_w,
    const float* __restrict__ Ws_b, const float* __restrict__ Wx,
    const float* __restrict__ b_cell, float* __restrict__ ws) {
  __shared__ float eL[16 * 260];
  __shared__ float wL[128 * 68];
  const int rt = blockIdx.x / 18, jb = blockIdx.x % 18;
  if (blockIdx.x == 0) {
    for (int i = threadIdx.x; i < 16384; i += 256) ws[OFF_HSH + i] = 0.f;
    unsigned* bar = (unsigned*)(ws + OFF_BAR);
    for (int i = threadIdx.x; i < 1024; i += 256) bar[i] = 0u;
  }
  for (int i = 0; i < 16; ++i) {
    int xi = x[rt * 16 + i];
    eL[i * 260 + threadIdx.x] = embed[xi * 256 + threadIdx.x];
  }
  const float* W; const float* bias1; const float* bias2 = nullptr;
  int ldw, wcol0, j0, ostride; float* out;
  if (jb < 8)       { W = W_ih; ldw = 256; wcol0 = 0;   j0 = jb * 128;        out = ws + OFF_X1; ostride = 1024; bias1 = b_ih; bias2 = b_hh; }
  else if (jb < 16) { W = Wx;   ldw = 256; wcol0 = 0;   j0 = (jb - 8) * 128;  out = ws + OFF_XX; ostride = 1024; bias1 = b_cell; }
  else              { W = Ws_w; ldw = 768; wcol0 = 512; j0 = (jb - 16) * 128; out = ws + OFF_A;  ostride = 256;  bias1 = Ws_b; }
  float acc[8];
  #pragma unroll
  for (int u = 0; u < 8; ++u) acc[u] = 0.f;
  tile_mm(W, ldw, wcol0, j0, eL, wL, acc);
  const int i = threadIdx.x >> 4, jj = threadIdx.x & 15;
  const int r = rt * 16 + i;
  #pragma unroll
  for (int u = 0; u < 8; ++u) {
    int j = j0 + jj + (u << 4);
    float bv = bias1[j] + (bias2 ? bias2[j] : 0.f);
    out[r * ostride + j] = acc[u] + bv;
  }
}

// K2: shared LSTM. grid 128 = 16 batches x 8 WGs, 512 threads.
// W_hh quarter-rows in registers; one flag-barrier per step.
__global__ __launch_bounds__(512) void k2_shared_lstm(
    const float* __restrict__ W_hh, float* __restrict__ ws) {
  const int b = blockIdx.x & 15, j = blockIdx.x >> 4;
  const int t = threadIdx.x;
  const int rl = t >> 2, q = t & 3;          // rl 0..127, q 0..3
  const int grow = ((rl >> 5) << 8) + (j << 5) + (rl & 31);
  __shared__ float x1L[64 * 128];
  __shared__ __align__(16) float hL[256];
  __shared__ float gA[128];
  unsigned* flg = (unsigned*)(ws + OFF_BAR) + b * 16;
  float* hsh = ws + OFF_HSH;
  float* sh  = ws + OFF_SH;
  const float* X1 = ws + OFF_X1;

  float4 wv[16];
  {
    const float* wp = W_hh + grow * 256 + (q << 6);
    #pragma unroll
    for (int m = 0; m < 16; ++m) wv[m] = *(const float4*)(wp + 4 * m);
  }
  for (int v = t; v < 8192; v += 512) {
    int st = v >> 7, r = v & 127;
    int col = ((r >> 5) << 8) + (j << 5) + (r & 31);
    x1L[v] = X1[(b * 64 + st) * 1024 + col];
  }
  float c_reg = 0.f;
  __syncthreads();

  for (int st = 0; st < 64; ++st) {
    const int par = st & 1;
    if (t < 8) { while ((int)gloadU(flg + t) < st) {} }
    __syncthreads();
    if (t < 256) hL[t] = gload(hsh + par * 4096 + b * 256 + t);
    __syncthreads();
    float p = 0.f;
    const float* hp = hL + (q << 6);
    #pragma unroll
    for (int m = 0; m < 16; ++m) {
      float4 h4 = *(const float4*)(hp + 4 * m);
      p += wv[m].x * h4.x + wv[m].y * h4.y + wv[m].z * h4.z + wv[m].w * h4.w;
    }
    p += __shfl_xor(p, 1); p += __shfl_xor(p, 2);
    if (q == 0) gA[rl] = p + x1L[st * 128 + rl];
    __syncthreads();
    if (t < 32) {
      float gi = gA[t], gf = gA[32 + t], gg = gA[64 + t], go = gA[96 + t];
      c_reg = sigf(gf) * c_reg + sigf(gi) * tanhfast(gg);
      float hn = sigf(go) * tanhfast(c_reg);
      int nn = (j << 5) + t;
      gstore(hsh + (par ^ 1) * 4096 + b * 256 + nn, hn);
      sh[(b * 64 + st) * 256 + nn] = hn;
    }
    __syncthreads();   // drains vmcnt: h stores globally visible before flag
    if (t == 0) gstoreU(flg + j, (unsigned)(st + 1));
  }
}

// K3: A += shared@Ws1^T ; SWM = shared@Wm^T.
__global__ __launch_bounds__(256) void k3_precompute2(
    const float* __restrict__ Ws_w, const float* __restrict__ Wm,
    float* __restrict__ ws) {
  __shared__ float eL[16 * 260];
  __shared__ float wL[128 * 68];
  const int rt = blockIdx.x / 10, jb = blockIdx.x % 10;
  const float* sh = ws + OFF_SH;
  for (int i = 0; i < 16; ++i)
    eL[i * 260 + threadIdx.x] = sh[(rt * 16 + i) * 256 + threadIdx.x];
  const float* W; int ldw, wcol0, j0, ostride; float* out; bool addmode;
  if (jb < 8) { W = Wm;   ldw = 256; wcol0 = 0; j0 = jb * 128;       out = ws + OFF_SWM; ostride = 1024; addmode = false; }
  else        { W = Ws_w; ldw = 768; wcol0 = 0; j0 = (jb - 8) * 128; out = ws + OFF_A;   ostride = 256;  addmode = true; }
  float acc[8];
  #pragma unroll
  for (int u = 0; u < 8; ++u) acc[u] = 0.f;
  tile_mm(W, ldw, wcol0, j0, eL, wL, acc);
  const int i = threadIdx.x >> 4, jj = threadIdx.x & 15;
  const int r = rt * 16 + i;
  #pragma unroll
  for (int u = 0; u < 8; ++u) {
    int j = j0 + jj + (u << 4);
    if (addmode) out[r * ostride + j] += acc[u];
    else         out[r * ostride + j]  = acc[u];
  }
}

// K4: task LSTM + attention. grid 128 = 16 batches x 8 WGs, 512 threads.
// ONE flag-barrier per step: hw/Si/softmax replicated per-WG; Ws2 + Wh in regs.
__global__ __launch_bounds__(512) void k4_task_lstm(
    const int* __restrict__ mask, const float* __restrict__ Ws_w,
    const float* __restrict__ Us_w, const float* __restrict__ Wh,
    const float* __restrict__ fc_w, const float* __restrict__ fc_b,
    float* __restrict__ ws, float* __restrict__ out) {
  const int b = blockIdx.x & 15, j = blockIdx.x >> 4;
  const int t = threadIdx.x;
  const int rl = t >> 2, q = t & 3;                     // g rows: rl 0..127
  const int grow = ((rl >> 5) << 8) + (j << 5) + (rl & 31);
  const int row2 = t >> 1, half2 = t & 1;               // Ws2 rows: 0..255
  const int sr = t >> 3, c = t & 7;                     // Si rows: 0..63

  __shared__ __align__(16) float aL[64 * 260];          // 66560 B
  __shared__ __align__(16) float swmB[4 * 128 * 20];    // 40960 B  [q][rl][s-16chunk]
  __shared__ __align__(16) float xx2[2 * 128];
  __shared__ __align__(16) float hL[256];
  __shared__ __align__(16) float hwL[256];
  __shared__ __align__(16) float usL[256];
  __shared__ __align__(16) float attL[64];
  __shared__ float siL[64];
  __shared__ float gA[128];
  __shared__ int   mL[64];

  unsigned* flg = (unsigned*)(ws + OFF_BAR) + 256 + b * 16;
  const float* A   = ws + OFF_A;
  const float* SWM = ws + OFF_SWM;
  const float* Xx  = ws + OFF_XX;
  float* hta = ws + OFF_HTA;

  // ---- weights into registers ----
  float4 w2v[32];   // Ws2 half-row (row2, cols half2*128..+128)
  {
    const float* p2 = Ws_w + row2 * 768 + 256 + (half2 << 7);
    #pragma unroll
    for (int m = 0; m < 32; ++m) w2v[m] = *(const float4*)(p2 + 4 * m);
  }
  float4 whv[16];   // Wh quarter-row (grow, cols q*64..+64)
  {
    const float* pw = Wh + grow * 256 + (q << 6);
    #pragma unroll
    for (int m = 0; m < 16; ++m) whv[m] = *(const float4*)(pw + 4 * m);
  }
  // ---- LDS staging ----
  for (int v = t; v < 64 * 256; v += 512) {
    int s = v >> 8, k = v & 255;
    aL[s * 260 + k] = A[(b * 64 + s) * 256 + k];
  }
  for (int v = t; v < 8192; v += 512) {
    int s = v >> 7, r = v & 127;
    int col = ((r >> 5) << 8) + (j << 5) + (r & 31);
    swmB[(s >> 4) * 2560 + r * 20 + (s & 15)] = SWM[(b * 64 + s) * 1024 + col];
  }
  if (t < 256) usL[t] = Us_w[t];
  if (t < 64) mL[t] = mask[b * 64 + t];
  if (t < 128) {
    int col = ((t >> 5) << 8) + (j << 5) + (t & 31);
    xx2[t] = Xx[(b * 64 + 0) * 1024 + col];
  }
  float c_reg = 0.f;
  __syncthreads();

  for (int st = 0; st < 64; ++st) {
    const int par = st & 1;
    // stage next step's Xx row-slice (overlaps with barrier wait)
    if (st + 1 < 64 && t < 128) {
      int col = ((t >> 5) << 8) + (j << 5) + (t & 31);
      xx2[((st + 1) & 1) * 128 + t] = Xx[(b * 64 + st + 1) * 1024 + col];
    }
    if (t < 8) { while ((int)gloadU(flg + t) < st) {} }
    __syncthreads();
    if (t < 256) hL[t] = gload(hta + par * 4096 + b * 256 + t);
    __syncthreads();
    // ---- hw = h @ Ws2^T (replicated across WGs) ----
    {
      float p = 0.f;
      const float* hp = hL + (half2 << 7);
      #pragma unroll
      for (int m = 0; m < 32; ++m) {
        float4 h4 = *(const float4*)(hp + 4 * m);
        p += w2v[m].x * h4.x + w2v[m].y * h4.y + w2v[m].z * h4.z + w2v[m].w * h4.w;
      }
      p += __shfl_xor(p, 1);
      if (half2 == 0) hwL[row2] = p;
    }
    __syncthreads();
    // ---- Si[sr] = sum_k Us[k] * tanh(A[sr][k] + hw[k]) ----
    {
      float acc = 0.f;
      const float* ab = aL + sr * 260 + (c << 5);
      const float* ub = usL + (c << 5);
      const float* hb = hwL + (c << 5);
      #pragma unroll
      for (int m = 0; m < 8; ++m) {
        float4 a4 = *(const float4*)(ab + 4 * m);
        float4 u4 = *(const float4*)(ub + 4 * m);
        float4 h4 = *(const float4*)(hb + 4 * m);
        acc += u4.x * tanhfast(a4.x + h4.x) + u4.y * tanhfast(a4.y + h4.y)
             + u4.z * tanhfast(a4.z + h4.z) + u4.w * tanhfast(a4.w + h4.w);
      }
      acc += __shfl_xor(acc, 1); acc += __shfl_xor(acc, 2); acc += __shfl_xor(acc, 4);
      if (c == 0) siL[sr] = mL[sr] ? acc : NEGV;
    }
    __syncthreads();
    // ---- softmax over 64 (wave 0) ----
    if (t < 64) {
      float v = siL[t];
      float mx = v;
      #pragma unroll
      for (int d = 1; d < 64; d <<= 1) mx = fmaxf(mx, __shfl_xor(mx, d));
      float e = __expf(v - mx);
      float ssum = e;
      #pragma unroll
      for (int d = 1; d < 64; d <<= 1) ssum += __shfl_xor(ssum, d);
      attL[t] = e / ssum;
    }
    __syncthreads();
    // ---- g[rl] = Xx + h@Wh^T + att@SWM (quarter dots, reduce over q) ----
    {
      float p = 0.f;
      const float* hp = hL + (q << 6);
      #pragma unroll
      for (int m = 0; m < 16; ++m) {
        float4 h4 = *(const float4*)(hp + 4 * m);
        p += whv[m].x * h4.x + whv[m].y * h4.y + whv[m].z * h4.z + whv[m].w * h4.w;
      }
      const float* sb = swmB + q * 2560 + rl * 20;
      const float* atb = attL + (q << 4);
      #pragma unroll
      for (int i2 = 0; i2 < 4; ++i2) {
        float4 s4 = *(const float4*)(sb + 4 * i2);
        float4 a4 = *(const float4*)(atb + 4 * i2);
        p += s4.x * a4.x + s4.y * a4.y + s4.z * a4.z + s4.w * a4.w;
      }
      p += __shfl_xor(p, 1); p += __shfl_xor(p, 2);
      if (q == 0) gA[rl] = p + xx2[par * 128 + rl];
    }
    __syncthreads();
    if (t < 32) {
      float gi = gA[t], gf = gA[32 + t], gg = gA[64 + t], go = gA[96 + t];
      c_reg = sigf(gf) * c_reg + sigf(gi) * tanhfast(gg);
      float hn = sigf(go) * tanhfast(c_reg);
      gstore(hta + (par ^ 1) * 4096 + b * 256 + (j << 5) + t, hn);
    }
    __syncthreads();   // drains vmcnt before flag store
    if (t == 0) gstoreU(flg + j, (unsigned)(st + 1));
  }

  // ---- final classifier (WG j==0 per batch) ----
  if (j == 0) {
    if (t < 8) { while ((int)gloadU(flg + t) < 64) {} }
    __syncthreads();
    float v = 0.f;
    if (t < 256) v = gload(hta + 0 * 4096 + b * 256 + t) * fc_w[t];
    #pragma unroll
    for (int d = 1; d < 64; d <<= 1) v += __shfl_xor(v, d);
    if ((t & 63) == 0) siL[t >> 6] = v;
    __syncthreads();
    if (t == 0) {
      float s = siL[0] + siL[1] + siL[2] + siL[3];
      out[b] = sigf(s + fc_b[0]);
    }
  }
}

extern "C" void kernel_launch(void* const* d_in, const int* in_sizes, int n_in,
                              void* d_out, int out_size, void* d_ws, size_t ws_size,
                              hipStream_t stream) {
  const int*   x      = (const int*)d_in[0];
  const int*   mask   = (const int*)d_in[1];
  const float* embed  = (const float*)d_in[3];
  const float* W_ih   = (const float*)d_in[4];
  const float* W_hh   = (const float*)d_in[5];
  const float* b_ih   = (const float*)d_in[6];
  const float* b_hh   = (const float*)d_in[7];
  const float* Ws_w   = (const float*)d_in[8];
  const float* Ws_b   = (const float*)d_in[9];
  const float* Us_w   = (const float*)d_in[10];
  const float* Wx     = (const float*)d_in[12];
  const float* Wh     = (const float*)d_in[13];
  const float* Wm     = (const float*)d_in[14];
  const float* b_cell = (const float*)d_in[15];
  const float* fc_w   = (const float*)d_in[16];
  const float* fc_b   = (const float*)d_in[17];
  float* ws  = (float*)d_ws;
  float* out = (float*)d_out;

  k1_precompute<<<dim3(1152), dim3(256), 0, stream>>>(
      x, embed, W_ih, b_ih, b_hh, Ws_w, Ws_b, Wx, b_cell, ws);
  k2_shared_lstm<<<dim3(128), dim3(512), 0, stream>>>(W_hh, ws);
  k3_precompute2<<<dim3(640), dim3(256), 0, stream>>>(Ws_w, Wm, ws);
  k4_task_lstm<<<dim3(128), dim3(512), 0, stream>>>(
      mask, Ws_w, Us_w, Wh, fc_w, fc_b, ws, out);
}

// Round 3
// 642.037 us; speedup vs baseline: 1.6735x; 1.1597x over previous
//
#include <hip/hip_runtime.h>

#define NEGV -1e9f

// workspace layout (float offsets)
#define OFF_X1   0u               // 1048576  emb@W_ih^T + b
#define OFF_XX   1048576u         // 1048576  emb@Wx^T + b_cell
#define OFF_A    2097152u         // 262144   Ws_b + emb@Ws3^T (+ sh@Ws1^T)
#define OFF_SH   2359296u         // 262144   shared LSTM outputs
#define OFF_SWM  2621440u         // 1048576  shared@Wm^T
#define OFF_HX2  3670016u         // 16384 floats = 2 slots x 16 x 256 u64 (k2 h exchange)
#define OFF_HX4  3686400u         // 16384 floats (k4 h exchange)

__device__ __forceinline__ float sigf(float x) { return 1.f / (1.f + __expf(-x)); }
__device__ __forceinline__ float tanhfast(float x) {
  float e = __expf(2.f * x);
  return 1.f - __fdividef(2.f, e + 1.f);
}

__device__ __forceinline__ unsigned long long gloadU64(const unsigned long long* p) {
  return __hip_atomic_load(p, __ATOMIC_RELAXED, __HIP_MEMORY_SCOPE_AGENT);
}
__device__ __forceinline__ void gstoreU64(unsigned long long* p, unsigned long long v) {
  __hip_atomic_store(p, v, __ATOMIC_RELAXED, __HIP_MEMORY_SCOPE_AGENT);
}

// 16-row x 128-col output tile GEMM helper, K=256. eL: [16][260], wL: [128][68]
__device__ __forceinline__ void tile_mm(const float* __restrict__ W, int ldw, int wcol0,
                                        int j0, const float* eL, float* wL, float acc[8]) {
  const int i = threadIdx.x >> 4, jj = threadIdx.x & 15;
  for (int kc = 0; kc < 4; ++kc) {
    __syncthreads();
    const int k0 = kc * 64;
    #pragma unroll
    for (int m = 0; m < 32; ++m) {
      int v = threadIdx.x + (m << 8);
      int row = v >> 6, col = v & 63;
      wL[row * 68 + col] = W[(j0 + row) * ldw + wcol0 + k0 + col];
    }
    __syncthreads();
    const float* ebase = eL + i * 260 + k0;
    #pragma unroll 4
    for (int k4 = 0; k4 < 16; ++k4) {
      float4 e4 = *(const float4*)(ebase + k4 * 4);
      #pragma unroll
      for (int u = 0; u < 8; ++u) {
        float4 w4 = *(const float4*)(wL + (jj + (u << 4)) * 68 + k4 * 4);
        acc[u] += e4.x * w4.x + e4.y * w4.y + e4.z * w4.z + e4.w * w4.w;
      }
    }
  }
}

// K1: emb gather + X1 = emb@W_ih^T + (b_ih+b_hh); Xx = emb@Wx^T + b_cell;
//     A = emb@Ws3^T + Ws_b. Also zero-inits h exchange buffers (tag=0, val=0).
__global__ __launch_bounds__(256) void k1_precompute(
    const int* __restrict__ x, const float* __restrict__ embed,
    const float* __restrict__ W_ih, const float* __restrict__ b_ih,
    const float* __restrict__ b_hh, const float* __restrict__ Ws_w,
    const float* __restrict__ Ws_b, const float* __restrict__ Wx,
    const float* __restrict__ b_cell, float* __restrict__ ws) {
  __shared__ float eL[16 * 260];
  __shared__ float wL[128 * 68];
  const int rt = blockIdx.x / 18, jb = blockIdx.x % 18;
  if (blockIdx.x == 0) {
    for (int i = threadIdx.x; i < 32768; i += 256) ws[OFF_HX2 + i] = 0.f;
  }
  for (int i = 0; i < 16; ++i) {
    int xi = x[rt * 16 + i];
    eL[i * 260 + threadIdx.x] = embed[xi * 256 + threadIdx.x];
  }
  const float* W; const float* bias1; const float* bias2 = nullptr;
  int ldw, wcol0, j0, ostride; float* out;
  if (jb < 8)       { W = W_ih; ldw = 256; wcol0 = 0;   j0 = jb * 128;        out = ws + OFF_X1; ostride = 1024; bias1 = b_ih; bias2 = b_hh; }
  else if (jb < 16) { W = Wx;   ldw = 256; wcol0 = 0;   j0 = (jb - 8) * 128;  out = ws + OFF_XX; ostride = 1024; bias1 = b_cell; }
  else              { W = Ws_w; ldw = 768; wcol0 = 512; j0 = (jb - 16) * 128; out = ws + OFF_A;  ostride = 256;  bias1 = Ws_b; }
  float acc[8];
  #pragma unroll
  for (int u = 0; u < 8; ++u) acc[u] = 0.f;
  tile_mm(W, ldw, wcol0, j0, eL, wL, acc);
  const int i = threadIdx.x >> 4, jj = threadIdx.x & 15;
  const int r = rt * 16 + i;
  #pragma unroll
  for (int u = 0; u < 8; ++u) {
    int j = j0 + jj + (u << 4);
    float bv = bias1[j] + (bias2 ? bias2[j] : 0.f);
    out[r * ostride + j] = acc[u] + bv;
  }
}

// K2: shared LSTM. grid 128 = 16 batches x 8 WGs, 256 threads.
// W_hh half-rows (128 VGPR) in registers; fused (tag|val) h exchange.
__global__ __launch_bounds__(256, 1) void k2_shared_lstm(
    const float* __restrict__ W_hh, float* __restrict__ ws) {
  const int b = blockIdx.x & 15, j = blockIdx.x >> 4;
  const int t = threadIdx.x;
  const int rl = t >> 1, half = t & 1;         // rl 0..127
  const int grow = ((rl >> 5) << 8) + (j << 5) + (rl & 31);
  __shared__ float x1L[64 * 128];
  __shared__ __align__(16) float hL[256];
  __shared__ float gA[128];
  unsigned long long* hx = (unsigned long long*)(ws + OFF_HX2);
  float* sh = ws + OFF_SH;
  const float* X1 = ws + OFF_X1;

  float4 wv[32];
  {
    const float* wp = W_hh + grow * 256 + (half << 7);
    #pragma unroll
    for (int m = 0; m < 32; ++m) wv[m] = *(const float4*)(wp + 4 * m);
  }
  for (int v = t; v < 8192; v += 256) {
    int st = v >> 7, r = v & 127;
    int col = ((r >> 5) << 8) + (j << 5) + (r & 31);
    x1L[v] = X1[(b * 64 + st) * 1024 + col];
  }
  float c_reg = 0.f;
  __syncthreads();

  for (int st = 0; st < 64; ++st) {
    {
      const unsigned long long* p = hx + (unsigned)(st & 1) * 4096u + b * 256 + t;
      unsigned long long v = gloadU64(p);
      while ((unsigned)(v >> 32) < (unsigned)st) v = gloadU64(p);
      hL[t] = __uint_as_float((unsigned)v);
    }
    __syncthreads();
    float pa = 0.f, pb = 0.f;
    const float* hp = hL + (half << 7);
    #pragma unroll
    for (int m = 0; m < 16; ++m) {
      float4 h0 = *(const float4*)(hp + 8 * m);
      float4 h1 = *(const float4*)(hp + 8 * m + 4);
      float4 w0 = wv[2 * m], w1 = wv[2 * m + 1];
      pa += w0.x * h0.x + w0.y * h0.y + w0.z * h0.z + w0.w * h0.w;
      pb += w1.x * h1.x + w1.y * h1.y + w1.z * h1.z + w1.w * h1.w;
    }
    float p = pa + pb;
    p += __shfl_xor(p, 1);
    if (half == 0) gA[rl] = p + x1L[st * 128 + rl];
    __syncthreads();
    if (t < 32) {
      float gi = gA[t], gf = gA[32 + t], gg = gA[64 + t], go = gA[96 + t];
      c_reg = sigf(gf) * c_reg + sigf(gi) * tanhfast(gg);
      float hn = sigf(go) * tanhfast(c_reg);
      sh[(b * 64 + st) * 256 + (j << 5) + t] = hn;
      unsigned long long pv = ((unsigned long long)(unsigned)(st + 1) << 32)
                            | (unsigned long long)__float_as_uint(hn);
      gstoreU64(hx + (unsigned)((st + 1) & 1) * 4096u + b * 256 + (j << 5) + t, pv);
    }
    // no trailing sync: next-step writers of hL/gA first pass the poll,
    // which requires this WG's tag store (issued after all reads of gA/hL).
  }
}

// K3: A += shared@Ws1^T ; SWM = shared@Wm^T.
__global__ __launch_bounds__(256) void k3_precompute2(
    const float* __restrict__ Ws_w, const float* __restrict__ Wm,
    float* __restrict__ ws) {
  __shared__ float eL[16 * 260];
  __shared__ float wL[128 * 68];
  const int rt = blockIdx.x / 10, jb = blockIdx.x % 10;
  const float* sh = ws + OFF_SH;
  for (int i = 0; i < 16; ++i)
    eL[i * 260 + threadIdx.x] = sh[(rt * 16 + i) * 256 + threadIdx.x];
  const float* W; int ldw, wcol0, j0, ostride; float* out; bool addmode;
  if (jb < 8) { W = Wm;   ldw = 256; wcol0 = 0; j0 = jb * 128;       out = ws + OFF_SWM; ostride = 1024; addmode = false; }
  else        { W = Ws_w; ldw = 768; wcol0 = 0; j0 = (jb - 8) * 128; out = ws + OFF_A;   ostride = 256;  addmode = true; }
  float acc[8];
  #pragma unroll
  for (int u = 0; u < 8; ++u) acc[u] = 0.f;
  tile_mm(W, ldw, wcol0, j0, eL, wL, acc);
  const int i = threadIdx.x >> 4, jj = threadIdx.x & 15;
  const int r = rt * 16 + i;
  #pragma unroll
  for (int u = 0; u < 8; ++u) {
    int j = j0 + jj + (u << 4);
    if (addmode) out[r * ostride + j] += acc[u];
    else         out[r * ostride + j]  = acc[u];
  }
}

// K4: task LSTM + attention. grid 128 = 16 batches x 8 WGs, 512 threads.
// launch_bounds(512,2): 1 WG/CU, 256-VGPR budget -> weights stay in registers.
__global__ __launch_bounds__(512, 2) void k4_task_lstm(
    const int* __restrict__ mask, const float* __restrict__ Ws_w,
    const float* __restrict__ Us_w, const float* __restrict__ Wh,
    const float* __restrict__ fc_w, const float* __restrict__ fc_b,
    float* __restrict__ ws, float* __restrict__ out) {
  const int b = blockIdx.x & 15, j = blockIdx.x >> 4;
  const int t = threadIdx.x;
  const int rl = t >> 2, q = t & 3;                     // g rows: rl 0..127
  const int grow = ((rl >> 5) << 8) + (j << 5) + (rl & 31);
  const int row2 = t >> 1, half2 = t & 1;               // Ws2 rows: 0..255
  const int sr = t >> 3, c = t & 7;                     // Si rows: 0..63

  __shared__ __align__(16) float aL[64 * 260];          // 66560 B
  __shared__ __align__(16) float swmB[4 * 128 * 20];    // 40960 B [q][rl][s-16chunk]
  __shared__ __align__(16) float hL[256];
  __shared__ __align__(16) float hwL[256];
  __shared__ __align__(16) float usL[256];
  __shared__ __align__(16) float attL[64];
  __shared__ float siL[64];
  __shared__ float gA[128];
  __shared__ int   mL[64];

  unsigned long long* hx = (unsigned long long*)(ws + OFF_HX4);
  const float* A   = ws + OFF_A;
  const float* SWM = ws + OFF_SWM;
  const float* Xx  = ws + OFF_XX;

  // ---- weights into registers (192 VGPR) ----
  float4 w2v[32];   // Ws2 half-row (row2, cols half2*128..+128)
  {
    const float* p2 = Ws_w + row2 * 768 + 256 + (half2 << 7);
    #pragma unroll
    for (int m = 0; m < 32; ++m) w2v[m] = *(const float4*)(p2 + 4 * m);
  }
  float4 whv[16];   // Wh quarter-row (grow, cols q*64..+64)
  {
    const float* pw = Wh + grow * 256 + (q << 6);
    #pragma unroll
    for (int m = 0; m < 16; ++m) whv[m] = *(const float4*)(pw + 4 * m);
  }
  // ---- LDS staging ----
  for (int v = t; v < 64 * 256; v += 512) {
    int s = v >> 8, k = v & 255;
    aL[s * 260 + k] = A[(b * 64 + s) * 256 + k];
  }
  for (int v = t; v < 8192; v += 512) {
    int s = v >> 7, r = v & 127;
    int col = ((r >> 5) << 8) + (j << 5) + (r & 31);
    swmB[(s >> 4) * 2560 + r * 20 + (s & 15)] = SWM[(b * 64 + s) * 1024 + col];
  }
  if (t < 256) usL[t] = Us_w[t];
  if (t < 64) mL[t] = mask[b * 64 + t];
  float c_reg = 0.f;
  __syncthreads();

  for (int st = 0; st < 64; ++st) {
    // early register prefetch of this step's Xx element (used at end of g)
    float xx_r = 0.f;
    if (q == 0) xx_r = Xx[(b * 64 + st) * 1024 + grow];
    // ---- poll h (own element, fused tag|value) ----
    if (t < 256) {
      const unsigned long long* p = hx + (unsigned)(st & 1) * 4096u + b * 256 + t;
      unsigned long long v = gloadU64(p);
      while ((unsigned)(v >> 32) < (unsigned)st) v = gloadU64(p);
      hL[t] = __uint_as_float((unsigned)v);
    }
    __syncthreads();
    // ---- hw = h @ Ws2^T (replicated across WGs) ----
    {
      float pa = 0.f, pb = 0.f;
      const float* hp = hL + (half2 << 7);
      #pragma unroll
      for (int m = 0; m < 16; ++m) {
        float4 h0 = *(const float4*)(hp + 8 * m);
        float4 h1 = *(const float4*)(hp + 8 * m + 4);
        float4 w0 = w2v[2 * m], w1 = w2v[2 * m + 1];
        pa += w0.x * h0.x + w0.y * h0.y + w0.z * h0.z + w0.w * h0.w;
        pb += w1.x * h1.x + w1.y * h1.y + w1.z * h1.z + w1.w * h1.w;
      }
      float p = pa + pb;
      p += __shfl_xor(p, 1);
      if (half2 == 0) hwL[row2] = p;
    }
    __syncthreads();
    // ---- Si[sr] = sum_k Us[k] * tanh(A[sr][k] + hw[k]) ----
    {
      float acc = 0.f;
      const float* ab = aL + sr * 260 + (c << 5);
      const float* ub = usL + (c << 5);
      const float* hb = hwL + (c << 5);
      #pragma unroll
      for (int m = 0; m < 8; ++m) {
        float4 a4 = *(const float4*)(ab + 4 * m);
        float4 u4 = *(const float4*)(ub + 4 * m);
        float4 h4 = *(const float4*)(hb + 4 * m);
        acc += u4.x * tanhfast(a4.x + h4.x) + u4.y * tanhfast(a4.y + h4.y)
             + u4.z * tanhfast(a4.z + h4.z) + u4.w * tanhfast(a4.w + h4.w);
      }
      acc += __shfl_xor(acc, 1); acc += __shfl_xor(acc, 2); acc += __shfl_xor(acc, 4);
      if (c == 0) siL[sr] = mL[sr] ? acc : NEGV;
    }
    __syncthreads();
    // ---- softmax over 64 (wave 0) ----
    if (t < 64) {
      float v = siL[t];
      float mx = v;
      #pragma unroll
      for (int d = 1; d < 64; d <<= 1) mx = fmaxf(mx, __shfl_xor(mx, d));
      float e = __expf(v - mx);
      float ssum = e;
      #pragma unroll
      for (int d = 1; d < 64; d <<= 1) ssum += __shfl_xor(ssum, d);
      attL[t] = e / ssum;
    }
    __syncthreads();
    // ---- g[rl] = Xx + h@Wh^T + att@SWM (quarter dots, reduce over q) ----
    {
      float p = 0.f;
      const float* hp = hL + (q << 6);
      #pragma unroll
      for (int m = 0; m < 16; ++m) {
        float4 h4 = *(const float4*)(hp + 4 * m);
        p += whv[m].x * h4.x + whv[m].y * h4.y + whv[m].z * h4.z + whv[m].w * h4.w;
      }
      const float* sb = swmB + q * 2560 + rl * 20;
      const float* atb = attL + (q << 4);
      #pragma unroll
      for (int i2 = 0; i2 < 4; ++i2) {
        float4 s4 = *(const float4*)(sb + 4 * i2);
        float4 a4 = *(const float4*)(atb + 4 * i2);
        p += s4.x * a4.x + s4.y * a4.y + s4.z * a4.z + s4.w * a4.w;
      }
      p += __shfl_xor(p, 1); p += __shfl_xor(p, 2);
      if (q == 0) gA[rl] = p + xx_r;
    }
    __syncthreads();
    // ---- gates + publish (tag|value), no trailing sync needed ----
    if (t < 32) {
      float gi = gA[t], gf = gA[32 + t], gg = gA[64 + t], go = gA[96 + t];
      c_reg = sigf(gf) * c_reg + sigf(gi) * tanhfast(gg);
      float hn = sigf(go) * tanhfast(c_reg);
      unsigned long long pv = ((unsigned long long)(unsigned)(st + 1) << 32)
                            | (unsigned long long)__float_as_uint(hn);
      gstoreU64(hx + (unsigned)((st + 1) & 1) * 4096u + b * 256 + (j << 5) + t, pv);
    }
  }

  // ---- final classifier (WG j==0 per batch) ----
  if (j == 0) {
    float v = 0.f;
    if (t < 256) {
      const unsigned long long* p = hx + 0 * 4096u + b * 256 + t;  // slot 64&1==0
      unsigned long long vv = gloadU64(p);
      while ((unsigned)(vv >> 32) < 64u) vv = gloadU64(p);
      v = __uint_as_float((unsigned)vv) * fc_w[t];
    }
    #pragma unroll
    for (int d = 1; d < 64; d <<= 1) v += __shfl_xor(v, d);
    if ((t & 63) == 0) siL[t >> 6] = v;
    __syncthreads();
    if (t == 0) out[b] = sigf(siL[0] + siL[1] + siL[2] + siL[3] + fc_b[0]);
  }
}

extern "C" void kernel_launch(void* const* d_in, const int* in_sizes, int n_in,
                              void* d_out, int out_size, void* d_ws, size_t ws_size,
                              hipStream_t stream) {
  const int*   x      = (const int*)d_in[0];
  const int*   mask   = (const int*)d_in[1];
  const float* embed  = (const float*)d_in[3];
  const float* W_ih   = (const float*)d_in[4];
  const float* W_hh   = (const float*)d_in[5];
  const float* b_ih   = (const float*)d_in[6];
  const float* b_hh   = (const float*)d_in[7];
  const float* Ws_w   = (const float*)d_in[8];
  const float* Ws_b   = (const float*)d_in[9];
  const float* Us_w   = (const float*)d_in[10];
  const float* Wx     = (const float*)d_in[12];
  const float* Wh     = (const float*)d_in[13];
  const float* Wm     = (const float*)d_in[14];
  const float* b_cell = (const float*)d_in[15];
  const float* fc_w   = (const float*)d_in[16];
  const float* fc_b   = (const float*)d_in[17];
  float* ws  = (float*)d_ws;
  float* out = (float*)d_out;

  k1_precompute<<<dim3(1152), dim3(256), 0, stream>>>(
      x, embed, W_ih, b_ih, b_hh, Ws_w, Ws_b, Wx, b_cell, ws);
  k2_shared_lstm<<<dim3(128), dim3(256), 0, stream>>>(W_hh, ws);
  k3_precompute2<<<dim3(640), dim3(256), 0, stream>>>(Ws_w, Wm, ws);
  k4_task_lstm<<<dim3(128), dim3(512), 0, stream>>>(
      mask, Ws_w, Us_w, Wh, fc_w, fc_b, ws, out);
}

// Round 4
// 608.719 us; speedup vs baseline: 1.7651x; 1.0547x over previous
//
#include <hip/hip_runtime.h>

#define NEGV -1e9f

// workspace layout (float offsets)
#define OFF_X1   0u               // 1048576  emb@W_ih^T + b  (k2-only; k3 reuses as A_T)
#define OFF_XX   1048576u         // 1048576  emb@Wx^T + b_cell
#define OFF_A    2097152u         // 262144   Aemb = Ws_b + emb@Ws3^T (row-major)
#define OFF_SH   2359296u         // 262144   shared LSTM outputs
#define OFF_SWM  2621440u         // 1048576  shared@Wm^T
#define OFF_HX2  3670016u         // 16384 floats = 2 slots x 16 x 256 u64 (k2 h exchange)
#define OFF_HX4  3686400u         // 16384 floats (k4 h exchange)
#define OFF_AT   OFF_X1           // 262144   A transposed [b][k=256][s=64] (written by k3)

__device__ __forceinline__ float sigf(float x) { return 1.f / (1.f + __expf(-x)); }
__device__ __forceinline__ float tanhfast(float x) {
  float e = __expf(2.f * x);
  return 1.f - __fdividef(2.f, e + 1.f);
}

__device__ __forceinline__ unsigned long long gloadU64(const unsigned long long* p) {
  return __hip_atomic_load(p, __ATOMIC_RELAXED, __HIP_MEMORY_SCOPE_AGENT);
}
__device__ __forceinline__ void gstoreU64(unsigned long long* p, unsigned long long v) {
  __hip_atomic_store(p, v, __ATOMIC_RELAXED, __HIP_MEMORY_SCOPE_AGENT);
}

// 16-row x 128-col output tile GEMM helper, K=256. eL: [16][260], wL: [128][68]
__device__ __forceinline__ void tile_mm(const float* __restrict__ W, int ldw, int wcol0,
                                        int j0, const float* eL, float* wL, float acc[8]) {
  const int i = threadIdx.x >> 4, jj = threadIdx.x & 15;
  for (int kc = 0; kc < 4; ++kc) {
    __syncthreads();
    const int k0 = kc * 64;
    #pragma unroll
    for (int m = 0; m < 32; ++m) {
      int v = threadIdx.x + (m << 8);
      int row = v >> 6, col = v & 63;
      wL[row * 68 + col] = W[(j0 + row) * ldw + wcol0 + k0 + col];
    }
    __syncthreads();
    const float* ebase = eL + i * 260 + k0;
    #pragma unroll 4
    for (int k4 = 0; k4 < 16; ++k4) {
      float4 e4 = *(const float4*)(ebase + k4 * 4);
      #pragma unroll
      for (int u = 0; u < 8; ++u) {
        float4 w4 = *(const float4*)(wL + (jj + (u << 4)) * 68 + k4 * 4);
        acc[u] += e4.x * w4.x + e4.y * w4.y + e4.z * w4.z + e4.w * w4.w;
      }
    }
  }
}

// K1: emb gather + X1 = emb@W_ih^T + (b_ih+b_hh); Xx = emb@Wx^T + b_cell;
//     Aemb = emb@Ws3^T + Ws_b (row-major). Zero-inits both h exchange buffers.
__global__ __launch_bounds__(256) void k1_precompute(
    const int* __restrict__ x, const float* __restrict__ embed,
    const float* __restrict__ W_ih, const float* __restrict__ b_ih,
    const float* __restrict__ b_hh, const float* __restrict__ Ws_w,
    const float* __restrict__ Ws_b, const float* __restrict__ Wx,
    const float* __restrict__ b_cell, float* __restrict__ ws) {
  __shared__ float eL[16 * 260];
  __shared__ float wL[128 * 68];
  const int rt = blockIdx.x / 18, jb = blockIdx.x % 18;
  if (blockIdx.x == 0) {
    for (int i = threadIdx.x; i < 32768; i += 256) ws[OFF_HX2 + i] = 0.f;
  }
  for (int i = 0; i < 16; ++i) {
    int xi = x[rt * 16 + i];
    eL[i * 260 + threadIdx.x] = embed[xi * 256 + threadIdx.x];
  }
  const float* W; const float* bias1; const float* bias2 = nullptr;
  int ldw, wcol0, j0, ostride; float* out;
  if (jb < 8)       { W = W_ih; ldw = 256; wcol0 = 0;   j0 = jb * 128;        out = ws + OFF_X1; ostride = 1024; bias1 = b_ih; bias2 = b_hh; }
  else if (jb < 16) { W = Wx;   ldw = 256; wcol0 = 0;   j0 = (jb - 8) * 128;  out = ws + OFF_XX; ostride = 1024; bias1 = b_cell; }
  else              { W = Ws_w; ldw = 768; wcol0 = 512; j0 = (jb - 16) * 128; out = ws + OFF_A;  ostride = 256;  bias1 = Ws_b; }
  float acc[8];
  #pragma unroll
  for (int u = 0; u < 8; ++u) acc[u] = 0.f;
  tile_mm(W, ldw, wcol0, j0, eL, wL, acc);
  const int i = threadIdx.x >> 4, jj = threadIdx.x & 15;
  const int r = rt * 16 + i;
  #pragma unroll
  for (int u = 0; u < 8; ++u) {
    int j = j0 + jj + (u << 4);
    float bv = bias1[j] + (bias2 ? bias2[j] : 0.f);
    out[r * ostride + j] = acc[u] + bv;
  }
}

// K2: shared LSTM. grid 128 = 16 batches x 8 WGs, 256 threads.
// W_hh half-rows (128 VGPR) in registers; fused (tag|val) h exchange.
__global__ __launch_bounds__(256) __attribute__((amdgpu_waves_per_eu(1, 2)))
void k2_shared_lstm(
    const float* __restrict__ W_hh, float* __restrict__ ws) {
  const int b = blockIdx.x & 15, j = blockIdx.x >> 4;
  const int t = threadIdx.x;
  const int rl = t >> 1, half = t & 1;         // rl 0..127
  const int grow = ((rl >> 5) << 8) + (j << 5) + (rl & 31);
  __shared__ float x1L[64 * 128];
  __shared__ __align__(16) float hL[256];
  __shared__ float gA[128];
  unsigned long long* hx = (unsigned long long*)(ws + OFF_HX2);
  float* sh = ws + OFF_SH;
  const float* X1 = ws + OFF_X1;

  float4 wv[32];
  {
    const float* wp = W_hh + grow * 256 + (half << 7);
    #pragma unroll
    for (int m = 0; m < 32; ++m) wv[m] = *(const float4*)(wp + 4 * m);
  }
  for (int v = t; v < 8192; v += 256) {
    int st = v >> 7, r = v & 127;
    int col = ((r >> 5) << 8) + (j << 5) + (r & 31);
    x1L[v] = X1[(b * 64 + st) * 1024 + col];
  }
  float c_reg = 0.f;
  __syncthreads();

  for (int st = 0; st < 64; ++st) {
    {
      const unsigned long long* p = hx + (unsigned)(st & 1) * 4096u + b * 256 + t;
      unsigned long long v = gloadU64(p);
      while ((unsigned)(v >> 32) < (unsigned)st) v = gloadU64(p);
      hL[t] = __uint_as_float((unsigned)v);
    }
    __syncthreads();
    float pa = 0.f, pb = 0.f;
    const float* hp = hL + (half << 7);
    #pragma unroll
    for (int m = 0; m < 16; ++m) {
      float4 h0 = *(const float4*)(hp + 8 * m);
      float4 h1 = *(const float4*)(hp + 8 * m + 4);
      float4 w0 = wv[2 * m], w1 = wv[2 * m + 1];
      pa += w0.x * h0.x + w0.y * h0.y + w0.z * h0.z + w0.w * h0.w;
      pb += w1.x * h1.x + w1.y * h1.y + w1.z * h1.z + w1.w * h1.w;
    }
    float p = pa + pb;
    p += __shfl_xor(p, 1);
    if (half == 0) gA[rl] = p + x1L[st * 128 + rl];
    __syncthreads();
    if (t < 32) {
      float gi = gA[t], gf = gA[32 + t], gg = gA[64 + t], go = gA[96 + t];
      c_reg = sigf(gf) * c_reg + sigf(gi) * tanhfast(gg);
      float hn = sigf(go) * tanhfast(c_reg);
      sh[(b * 64 + st) * 256 + (j << 5) + t] = hn;
      unsigned long long pv = ((unsigned long long)(unsigned)(st + 1) << 32)
                            | (unsigned long long)__float_as_uint(hn);
      gstoreU64(hx + (unsigned)((st + 1) & 1) * 4096u + b * 256 + (j << 5) + t, pv);
    }
  }
}

// K3: A_T[b][k][s] = Aemb + shared@Ws1^T (transposed write into dead X1 buf);
//     SWM = shared@Wm^T (row-major as before).
__global__ __launch_bounds__(256) void k3_precompute2(
    const float* __restrict__ Ws_w, const float* __restrict__ Wm,
    float* __restrict__ ws) {
  __shared__ float eL[16 * 260];
  __shared__ float wL[128 * 68];
  const int rt = blockIdx.x / 10, jb = blockIdx.x % 10;
  const float* sh = ws + OFF_SH;
  for (int i = 0; i < 16; ++i)
    eL[i * 260 + threadIdx.x] = sh[(rt * 16 + i) * 256 + threadIdx.x];
  const float* W; int ldw, wcol0, j0; bool addmode;
  if (jb < 8) { W = Wm;   ldw = 256; wcol0 = 0; j0 = jb * 128;       addmode = false; }
  else        { W = Ws_w; ldw = 768; wcol0 = 0; j0 = (jb - 8) * 128; addmode = true; }
  float acc[8];
  #pragma unroll
  for (int u = 0; u < 8; ++u) acc[u] = 0.f;
  tile_mm(W, ldw, wcol0, j0, eL, wL, acc);
  const int i = threadIdx.x >> 4, jj = threadIdx.x & 15;
  const int r = rt * 16 + i;
  if (addmode) {
    const float* Aemb = ws + OFF_A;
    float* AT = ws + OFF_AT;
    const int bb = r >> 6, s = r & 63;
    #pragma unroll
    for (int u = 0; u < 8; ++u) {
      int j = j0 + jj + (u << 4);
      AT[bb * 16384 + j * 64 + s] = Aemb[r * 256 + j] + acc[u];
    }
  } else {
    float* out = ws + OFF_SWM;
    #pragma unroll
    for (int u = 0; u < 8; ++u) {
      int j = j0 + jj + (u << 4);
      out[r * 1024 + j] = acc[u];
    }
  }
}

// K4: task LSTM + attention. grid 128 = 16 batches x 8 WGs, 512 threads.
// amdgpu_waves_per_eu(2,2): 256-VGPR budget (LDS caps at 1 WG/CU anyway) so
// the 192 VGPRs of Ws2/Wh weights stay register-resident (no scratch reload).
__global__ __launch_bounds__(512) __attribute__((amdgpu_waves_per_eu(2, 2)))
void k4_task_lstm(
    const int* __restrict__ mask, const float* __restrict__ Ws_w,
    const float* __restrict__ Us_w, const float* __restrict__ Wh,
    const float* __restrict__ fc_w, const float* __restrict__ fc_b,
    float* __restrict__ ws, float* __restrict__ out) {
  const int b = blockIdx.x & 15, j = blockIdx.x >> 4;
  const int t = threadIdx.x;
  const int rl = t >> 2, q = t & 3;                     // g rows: rl 0..127
  const int grow = ((rl >> 5) << 8) + (j << 5) + (rl & 31);
  const int row2 = t >> 1, half2 = t & 1;               // Ws2 rows: 0..255
  const int wv8 = t >> 6, l64 = t & 63;                 // Si: wave k-chunk / s-lane

  __shared__ __align__(16) float aT[256 * 65];          // 66560 B  A^T [k][s] pad65
  __shared__ __align__(16) float swmB[4 * 128 * 20];    // 40960 B [s/16][rl][16]
  __shared__ __align__(16) float hL[256];
  __shared__ __align__(16) float hwL[256];
  __shared__ __align__(16) float usL[256];
  __shared__ __align__(16) float attL[64];
  __shared__ float psiL[8 * 64];
  __shared__ float gA[128];
  __shared__ float redL[4];
  __shared__ int   mL[64];

  unsigned long long* hx = (unsigned long long*)(ws + OFF_HX4);
  const float* AT  = ws + OFF_AT;
  const float* SWM = ws + OFF_SWM;
  const float* Xx  = ws + OFF_XX;

  // ---- weights into registers (192 VGPR) ----
  float4 w2v[32];   // Ws2 half-row (row2, cols half2*128..+128)
  {
    const float* p2 = Ws_w + row2 * 768 + 256 + (half2 << 7);
    #pragma unroll
    for (int m = 0; m < 32; ++m) w2v[m] = *(const float4*)(p2 + 4 * m);
  }
  float4 whv[16];   // Wh quarter-row (grow, cols q*64..+64)
  {
    const float* pw = Wh + grow * 256 + (q << 6);
    #pragma unroll
    for (int m = 0; m < 16; ++m) whv[m] = *(const float4*)(pw + 4 * m);
  }
  // ---- LDS staging ----
  // A^T: coalesced global read (AT is [b][k][s]); LDS banks (k+s)%32 -> free.
  for (int v = t; v < 16384; v += 512)
    aT[(v >> 6) * 65 + (v & 63)] = AT[b * 16384 + v];
  for (int v = t; v < 8192; v += 512) {
    int s = v >> 7, r = v & 127;
    int col = ((r >> 5) << 8) + (j << 5) + (r & 31);
    swmB[(s >> 4) * 2560 + r * 20 + (s & 15)] = SWM[(b * 64 + s) * 1024 + col];
  }
  if (t < 256) usL[t] = Us_w[t];
  if (t < 64) mL[t] = mask[b * 64 + t];
  float c_reg = 0.f;
  __syncthreads();

  for (int st = 0; st < 64; ++st) {
    // early register prefetch of this step's Xx element (used at end of g)
    float xx_r = 0.f;
    if (q == 0) xx_r = Xx[(b * 64 + st) * 1024 + grow];
    // ---- poll h (own element, fused tag|value) ----
    if (t < 256) {
      const unsigned long long* p = hx + (unsigned)(st & 1) * 4096u + b * 256 + t;
      unsigned long long v = gloadU64(p);
      while ((unsigned)(v >> 32) < (unsigned)st) v = gloadU64(p);
      hL[t] = __uint_as_float((unsigned)v);
    }
    __syncthreads();
    // ---- hw = h @ Ws2^T (replicated across WGs; weights in regs) ----
    {
      float pa = 0.f, pb = 0.f;
      const float* hp = hL + (half2 << 7);
      #pragma unroll
      for (int m = 0; m < 16; ++m) {
        float4 h0 = *(const float4*)(hp + 8 * m);
        float4 h1 = *(const float4*)(hp + 8 * m + 4);
        float4 w0 = w2v[2 * m], w1 = w2v[2 * m + 1];
        pa += w0.x * h0.x + w0.y * h0.y + w0.z * h0.z + w0.w * h0.w;
        pb += w1.x * h1.x + w1.y * h1.y + w1.z * h1.z + w1.w * h1.w;
      }
      float p = pa + pb;
      p += __shfl_xor(p, 1);
      if (half2 == 0) hwL[row2] = p;
    }
    __syncthreads();
    // ---- Si partials: wave wv8 owns k-chunk [32*wv8,+32), lane l64 owns s ----
    // aT reads: stride-1 across lanes (conflict-free b32); usL/hwL: broadcast.
    {
      float psi = 0.f;
      const int k0 = wv8 << 5;
      #pragma unroll 8
      for (int kk = 0; kk < 32; ++kk) {
        int k = k0 + kk;
        psi += usL[k] * tanhfast(aT[k * 65 + l64] + hwL[k]);
      }
      psiL[(wv8 << 6) + l64] = psi;
    }
    __syncthreads();
    // ---- reduce partials + mask + softmax (wave 0) ----
    if (t < 64) {
      float acc = 0.f;
      #pragma unroll
      for (int w = 0; w < 8; ++w) acc += psiL[(w << 6) + t];
      float v = mL[t] ? acc : NEGV;
      float mx = v;
      #pragma unroll
      for (int d = 1; d < 64; d <<= 1) mx = fmaxf(mx, __shfl_xor(mx, d));
      float e = __expf(v - mx);
      float ssum = e;
      #pragma unroll
      for (int d = 1; d < 64; d <<= 1) ssum += __shfl_xor(ssum, d);
      attL[t] = e / ssum;
    }
    __syncthreads();
    // ---- g[rl] = Xx + h@Wh^T + att@SWM (quarter dots, reduce over q) ----
    {
      float p = 0.f;
      const float* hp = hL + (q << 6);
      #pragma unroll
      for (int m = 0; m < 16; ++m) {
        float4 h4 = *(const float4*)(hp + 4 * m);
        p += whv[m].x * h4.x + whv[m].y * h4.y + whv[m].z * h4.z + whv[m].w * h4.w;
      }
      const float* sb = swmB + q * 2560 + rl * 20;
      const float* atb = attL + (q << 4);
      #pragma unroll
      for (int i2 = 0; i2 < 4; ++i2) {
        float4 s4 = *(const float4*)(sb + 4 * i2);
        float4 a4 = *(const float4*)(atb + 4 * i2);
        p += s4.x * a4.x + s4.y * a4.y + s4.z * a4.z + s4.w * a4.w;
      }
      p += __shfl_xor(p, 1); p += __shfl_xor(p, 2);
      if (q == 0) gA[rl] = p + xx_r;
    }
    __syncthreads();
    // ---- gates + publish (tag|value) ----
    if (t < 32) {
      float gi = gA[t], gf = gA[32 + t], gg = gA[64 + t], go = gA[96 + t];
      c_reg = sigf(gf) * c_reg + sigf(gi) * tanhfast(gg);
      float hn = sigf(go) * tanhfast(c_reg);
      unsigned long long pv = ((unsigned long long)(unsigned)(st + 1) << 32)
                            | (unsigned long long)__float_as_uint(hn);
      gstoreU64(hx + (unsigned)((st + 1) & 1) * 4096u + b * 256 + (j << 5) + t, pv);
    }
  }

  // ---- final classifier (WG j==0 per batch) ----
  if (j == 0) {
    float v = 0.f;
    if (t < 256) {
      const unsigned long long* p = hx + 0 * 4096u + b * 256 + t;  // slot 64&1==0
      unsigned long long vv = gloadU64(p);
      while ((unsigned)(vv >> 32) < 64u) vv = gloadU64(p);
      v = __uint_as_float((unsigned)vv) * fc_w[t];
    }
    #pragma unroll
    for (int d = 1; d < 64; d <<= 1) v += __shfl_xor(v, d);
    if (t < 256 && (t & 63) == 0) redL[t >> 6] = v;
    __syncthreads();
    if (t == 0) out[b] = sigf(redL[0] + redL[1] + redL[2] + redL[3] + fc_b[0]);
  }
}

extern "C" void kernel_launch(void* const* d_in, const int* in_sizes, int n_in,
                              void* d_out, int out_size, void* d_ws, size_t ws_size,
                              hipStream_t stream) {
  const int*   x      = (const int*)d_in[0];
  const int*   mask   = (const int*)d_in[1];
  const float* embed  = (const float*)d_in[3];
  const float* W_ih   = (const float*)d_in[4];
  const float* W_hh   = (const float*)d_in[5];
  const float* b_ih   = (const float*)d_in[6];
  const float* b_hh   = (const float*)d_in[7];
  const float* Ws_w   = (const float*)d_in[8];
  const float* Ws_b   = (const float*)d_in[9];
  const float* Us_w   = (const float*)d_in[10];
  const float* Wx     = (const float*)d_in[12];
  const float* Wh     = (const float*)d_in[13];
  const float* Wm     = (const float*)d_in[14];
  const float* b_cell = (const float*)d_in[15];
  const float* fc_w   = (const float*)d_in[16];
  const float* fc_b   = (const float*)d_in[17];
  float* ws  = (float*)d_ws;
  float* out = (float*)d_out;

  k1_precompute<<<dim3(1152), dim3(256), 0, stream>>>(
      x, embed, W_ih, b_ih, b_hh, Ws_w, Ws_b, Wx, b_cell, ws);
  k2_shared_lstm<<<dim3(128), dim3(256), 0, stream>>>(W_hh, ws);
  k3_precompute2<<<dim3(640), dim3(256), 0, stream>>>(Ws_w, Wm, ws);
  k4_task_lstm<<<dim3(128), dim3(512), 0, stream>>>(
      mask, Ws_w, Us_w, Wh, fc_w, fc_b, ws, out);
}

// Round 5
// 436.415 us; speedup vs baseline: 2.4620x; 1.3948x over previous
//
#include <hip/hip_runtime.h>

#define NEGV -1e9f

// workspace layout (float offsets)
#define OFF_X1   0u               // 1048576  emb@W_ih^T + b  (k2-only; k3 reuses as A_T)
#define OFF_XX   1048576u         // 1048576  emb@Wx^T + b_cell
#define OFF_A    2097152u         // 262144   Aemb = Ws_b + emb@Ws3^T (row-major)
#define OFF_SH   2359296u         // 262144   shared LSTM outputs
#define OFF_SWM  2621440u         // 1048576  shared@Wm^T
#define OFF_HX2  3670016u         // 16384 floats = 2 slots x 16 x 256 u64 (k2 h exchange)
#define OFF_HX4  3686400u         // 16384 floats (k4 h exchange)
#define OFF_PSI  3702784u         // 32768 floats = 2 slots x 16 x 512 u64 (k4 psi exchange)
#define OFF_AT   OFF_X1           // 262144   A transposed [b][k=256][s=64] (written by k3)

__device__ __forceinline__ float sigf(float x) { return 1.f / (1.f + __expf(-x)); }
__device__ __forceinline__ float tanhfast(float x) {
  float e = __expf(2.f * x);
  return 1.f - __fdividef(2.f, e + 1.f);
}

__device__ __forceinline__ unsigned long long gloadU64(const unsigned long long* p) {
  return __hip_atomic_load(p, __ATOMIC_RELAXED, __HIP_MEMORY_SCOPE_AGENT);
}
__device__ __forceinline__ void gstoreU64(unsigned long long* p, unsigned long long v) {
  __hip_atomic_store(p, v, __ATOMIC_RELAXED, __HIP_MEMORY_SCOPE_AGENT);
}

// 16-row x 128-col output tile GEMM helper, K=256. eL: [16][260], wL: [128][68]
__device__ __forceinline__ void tile_mm(const float* __restrict__ W, int ldw, int wcol0,
                                        int j0, const float* eL, float* wL, float acc[8]) {
  const int i = threadIdx.x >> 4, jj = threadIdx.x & 15;
  for (int kc = 0; kc < 4; ++kc) {
    __syncthreads();
    const int k0 = kc * 64;
    #pragma unroll
    for (int m = 0; m < 32; ++m) {
      int v = threadIdx.x + (m << 8);
      int row = v >> 6, col = v & 63;
      wL[row * 68 + col] = W[(j0 + row) * ldw + wcol0 + k0 + col];
    }
    __syncthreads();
    const float* ebase = eL + i * 260 + k0;
    #pragma unroll 4
    for (int k4 = 0; k4 < 16; ++k4) {
      float4 e4 = *(const float4*)(ebase + k4 * 4);
      #pragma unroll
      for (int u = 0; u < 8; ++u) {
        float4 w4 = *(const float4*)(wL + (jj + (u << 4)) * 68 + k4 * 4);
        acc[u] += e4.x * w4.x + e4.y * w4.y + e4.z * w4.z + e4.w * w4.w;
      }
    }
  }
}

// K1: emb gather + X1 = emb@W_ih^T + (b_ih+b_hh); Xx = emb@Wx^T + b_cell;
//     Aemb = emb@Ws3^T + Ws_b (row-major). Zero-inits all exchange buffers.
__global__ __launch_bounds__(256) void k1_precompute(
    const int* __restrict__ x, const float* __restrict__ embed,
    const float* __restrict__ W_ih, const float* __restrict__ b_ih,
    const float* __restrict__ b_hh, const float* __restrict__ Ws_w,
    const float* __restrict__ Ws_b, const float* __restrict__ Wx,
    const float* __restrict__ b_cell, float* __restrict__ ws) {
  __shared__ float eL[16 * 260];
  __shared__ float wL[128 * 68];
  const int rt = blockIdx.x / 18, jb = blockIdx.x % 18;
  if (blockIdx.x == 0) {
    for (int i = threadIdx.x; i < 65536; i += 256) ws[OFF_HX2 + i] = 0.f;
  }
  for (int i = 0; i < 16; ++i) {
    int xi = x[rt * 16 + i];
    eL[i * 260 + threadIdx.x] = embed[xi * 256 + threadIdx.x];
  }
  const float* W; const float* bias1; const float* bias2 = nullptr;
  int ldw, wcol0, j0, ostride; float* out;
  if (jb < 8)       { W = W_ih; ldw = 256; wcol0 = 0;   j0 = jb * 128;        out = ws + OFF_X1; ostride = 1024; bias1 = b_ih; bias2 = b_hh; }
  else if (jb < 16) { W = Wx;   ldw = 256; wcol0 = 0;   j0 = (jb - 8) * 128;  out = ws + OFF_XX; ostride = 1024; bias1 = b_cell; }
  else              { W = Ws_w; ldw = 768; wcol0 = 512; j0 = (jb - 16) * 128; out = ws + OFF_A;  ostride = 256;  bias1 = Ws_b; }
  float acc[8];
  #pragma unroll
  for (int u = 0; u < 8; ++u) acc[u] = 0.f;
  tile_mm(W, ldw, wcol0, j0, eL, wL, acc);
  const int i = threadIdx.x >> 4, jj = threadIdx.x & 15;
  const int r = rt * 16 + i;
  #pragma unroll
  for (int u = 0; u < 8; ++u) {
    int j = j0 + jj + (u << 4);
    float bv = bias1[j] + (bias2 ? bias2[j] : 0.f);
    out[r * ostride + j] = acc[u] + bv;
  }
}

// K2: shared LSTM. grid 128 = 16 batches x 8 WGs, 512 threads.
// W_hh quarter-rows = 16 float4 = 64 VGPRs persistent -> fits 128, no spill.
__global__ __launch_bounds__(512) void k2_shared_lstm(
    const float* __restrict__ W_hh, float* __restrict__ ws) {
  const int b = blockIdx.x & 15, j = blockIdx.x >> 4;
  const int t = threadIdx.x;
  const int rl = t >> 2, q = t & 3;            // rl 0..127, q 0..3
  const int grow = ((rl >> 5) << 8) + (j << 5) + (rl & 31);
  __shared__ float x1L[64 * 128];
  __shared__ __align__(16) float hL[256];
  __shared__ float gA[128];
  unsigned long long* hx = (unsigned long long*)(ws + OFF_HX2);
  float* sh = ws + OFF_SH;
  const float* X1 = ws + OFF_X1;

  float4 wv[16];
  {
    const float* wp = W_hh + grow * 256 + (q << 6);
    #pragma unroll
    for (int m = 0; m < 16; ++m) wv[m] = *(const float4*)(wp + 4 * m);
  }
  for (int v = t; v < 8192; v += 512) {
    int st = v >> 7, r = v & 127;
    int col = ((r >> 5) << 8) + (j << 5) + (r & 31);
    x1L[v] = X1[(b * 64 + st) * 1024 + col];
  }
  float c_reg = 0.f;
  __syncthreads();

  for (int st = 0; st < 64; ++st) {
    if (t < 256) {
      const unsigned long long* p = hx + (unsigned)(st & 1) * 4096u + b * 256 + t;
      unsigned long long v = gloadU64(p);
      while ((unsigned)(v >> 32) < (unsigned)st) v = gloadU64(p);
      hL[t] = __uint_as_float((unsigned)v);
    }
    __syncthreads();
    float p = 0.f;
    const float* hp = hL + (q << 6);
    #pragma unroll
    for (int m = 0; m < 16; ++m) {
      float4 h4 = *(const float4*)(hp + 4 * m);
      p += wv[m].x * h4.x + wv[m].y * h4.y + wv[m].z * h4.z + wv[m].w * h4.w;
    }
    p += __shfl_xor(p, 1); p += __shfl_xor(p, 2);
    if (q == 0) gA[rl] = p + x1L[st * 128 + rl];
    __syncthreads();
    if (t < 32) {
      float gi = gA[t], gf = gA[32 + t], gg = gA[64 + t], go = gA[96 + t];
      c_reg = sigf(gf) * c_reg + sigf(gi) * tanhfast(gg);
      float hn = sigf(go) * tanhfast(c_reg);
      sh[(b * 64 + st) * 256 + (j << 5) + t] = hn;
      unsigned long long pv = ((unsigned long long)(unsigned)(st + 1) << 32)
                            | (unsigned long long)__float_as_uint(hn);
      gstoreU64(hx + (unsigned)((st + 1) & 1) * 4096u + b * 256 + (j << 5) + t, pv);
    }
  }
}

// K3: A_T[b][k][s] = Aemb + shared@Ws1^T (transposed write into dead X1 buf);
//     SWM = shared@Wm^T (row-major as before).
__global__ __launch_bounds__(256) void k3_precompute2(
    const float* __restrict__ Ws_w, const float* __restrict__ Wm,
    float* __restrict__ ws) {
  __shared__ float eL[16 * 260];
  __shared__ float wL[128 * 68];
  const int rt = blockIdx.x / 10, jb = blockIdx.x % 10;
  const float* sh = ws + OFF_SH;
  for (int i = 0; i < 16; ++i)
    eL[i * 260 + threadIdx.x] = sh[(rt * 16 + i) * 256 + threadIdx.x];
  const float* W; int ldw, wcol0, j0; bool addmode;
  if (jb < 8) { W = Wm;   ldw = 256; wcol0 = 0; j0 = jb * 128;       addmode = false; }
  else        { W = Ws_w; ldw = 768; wcol0 = 0; j0 = (jb - 8) * 128; addmode = true; }
  float acc[8];
  #pragma unroll
  for (int u = 0; u < 8; ++u) acc[u] = 0.f;
  tile_mm(W, ldw, wcol0, j0, eL, wL, acc);
  const int i = threadIdx.x >> 4, jj = threadIdx.x & 15;
  const int r = rt * 16 + i;
  if (addmode) {
    const float* Aemb = ws + OFF_A;
    float* AT = ws + OFF_AT;
    const int bb = r >> 6, s = r & 63;
    #pragma unroll
    for (int u = 0; u < 8; ++u) {
      int j = j0 + jj + (u << 4);
      AT[bb * 16384 + j * 64 + s] = Aemb[r * 256 + j] + acc[u];
    }
  } else {
    float* out = ws + OFF_SWM;
    #pragma unroll
    for (int u = 0; u < 8; ++u) {
      int j = j0 + jj + (u << 4);
      out[r * 1024 + j] = acc[u];
    }
  }
}

// K4: task LSTM + attention. grid 128 = 16 batches x 8 WGs, 512 threads.
// No hw replication: WG j owns hw rows [32j,32j+32) (Ws2 slice = 16 VGPRs) and
// the matching k-chunk of Si partials; psi partials exchanged (fused tag|val).
// Persistent regs ~80 -> fits the 128-VGPR budget, no scratch spill.
__global__ __launch_bounds__(512) void k4_task_lstm(
    const int* __restrict__ mask, const float* __restrict__ Ws_w,
    const float* __restrict__ Us_w, const float* __restrict__ Wh,
    const float* __restrict__ fc_w, const float* __restrict__ fc_b,
    float* __restrict__ ws, float* __restrict__ out) {
  const int b = blockIdx.x & 15, j = blockIdx.x >> 4;
  const int t = threadIdx.x;
  const int rl = t >> 2, q = t & 3;                     // g rows: rl 0..127
  const int grow = ((rl >> 5) << 8) + (j << 5) + (rl & 31);
  const int hwrow = t >> 4, hwc = t & 15;               // hw: 32 rows x 16 cols-of-16
  const int kq = t >> 6, sl = t & 63;                   // psi: wave k-subchunk / s lane

  __shared__ __align__(16) float swmB[4 * 128 * 20];    // 40960 B [s/16][rl][16]
  __shared__ __align__(16) float aTo[32 * 65];          // 8320 B  own A^T chunk [kk][s]
  __shared__ __align__(16) float hL[256];
  __shared__ float hwOwn[32];
  __shared__ float usOwn[32];
  __shared__ float part[8 * 64];
  __shared__ float psiA[512];
  __shared__ __align__(16) float attL[64];
  __shared__ float gA[128];
  __shared__ float redL[4];
  __shared__ int   mL[64];

  unsigned long long* hx   = (unsigned long long*)(ws + OFF_HX4);
  unsigned long long* psiX = (unsigned long long*)(ws + OFF_PSI);
  const float* AT  = ws + OFF_AT;
  const float* SWM = ws + OFF_SWM;
  const float* Xx  = ws + OFF_XX;

  // ---- weights into registers (~80 VGPR persistent) ----
  float4 w2v[4];    // Ws2 row (32j+hwrow), cols hwc*16..+16
  {
    const float* p2 = Ws_w + (j * 32 + hwrow) * 768 + 256 + (hwc << 4);
    #pragma unroll
    for (int m = 0; m < 4; ++m) w2v[m] = *(const float4*)(p2 + 4 * m);
  }
  float4 whv[16];   // Wh quarter-row (grow, cols q*64..+64)
  {
    const float* pw = Wh + grow * 256 + (q << 6);
    #pragma unroll
    for (int m = 0; m < 16; ++m) whv[m] = *(const float4*)(pw + 4 * m);
  }
  // ---- LDS staging ----
  for (int v = t; v < 2048; v += 512)   // own A^T k-chunk, coalesced
    aTo[(v >> 6) * 65 + (v & 63)] = AT[b * 16384 + j * 2048 + v];
  for (int v = t; v < 8192; v += 512) {
    int s = v >> 7, r = v & 127;
    int col = ((r >> 5) << 8) + (j << 5) + (r & 31);
    swmB[(s >> 4) * 2560 + r * 20 + (s & 15)] = SWM[(b * 64 + s) * 1024 + col];
  }
  if (t < 32) usOwn[t] = Us_w[j * 32 + t];
  if (t < 64) mL[t] = mask[b * 64 + t];
  float c_reg = 0.f;
  __syncthreads();

  for (int st = 0; st < 64; ++st) {
    // early register prefetch of this step's Xx element (used at end of g)
    float xx_r = 0.f;
    if (q == 0) xx_r = Xx[(b * 64 + st) * 1024 + grow];
    // ---- poll h (own element, fused tag|value) ----
    if (t < 256) {
      const unsigned long long* p = hx + (unsigned)(st & 1) * 4096u + b * 256 + t;
      unsigned long long v = gloadU64(p);
      while ((unsigned)(v >> 32) < (unsigned)st) v = gloadU64(p);
      hL[t] = __uint_as_float((unsigned)v);
    }
    __syncthreads();
    // ---- hw own rows: hw[32j+r] = h . Ws2[32j+r], 16 threads/row ----
    {
      const float* hp = hL + (hwc << 4);
      float p = 0.f;
      #pragma unroll
      for (int m = 0; m < 4; ++m) {
        float4 h4 = *(const float4*)(hp + 4 * m);
        p += w2v[m].x * h4.x + w2v[m].y * h4.y + w2v[m].z * h4.z + w2v[m].w * h4.w;
      }
      p += __shfl_xor(p, 1); p += __shfl_xor(p, 2);
      p += __shfl_xor(p, 4); p += __shfl_xor(p, 8);
      if (hwc == 0) hwOwn[hwrow] = p;
    }
    __syncthreads();
    // ---- psi partials over own k-chunk: lane owns s, wave owns 4 k's ----
    {
      float ps = 0.f;
      #pragma unroll
      for (int i2 = 0; i2 < 4; ++i2) {
        int kk = (kq << 2) + i2;
        ps += usOwn[kk] * tanhfast(aTo[kk * 65 + sl] + hwOwn[kk]);
      }
      part[(kq << 6) + sl] = ps;
    }
    __syncthreads();
    // ---- reduce 8 waves -> psi_j[s], publish (fused tag|val) ----
    if (t < 64) {
      float ps = 0.f;
      #pragma unroll
      for (int w = 0; w < 8; ++w) ps += part[(w << 6) + t];
      unsigned long long pv = ((unsigned long long)(unsigned)(st + 1) << 32)
                            | (unsigned long long)__float_as_uint(ps);
      gstoreU64(psiX + ((unsigned)(st & 1) * 16u + b) * 512u + (j << 6) + t, pv);
    }
    // ---- h@Wh^T partial (independent of attention; hides psi-poll latency) --
    float pwh = 0.f;
    {
      const float* hp = hL + (q << 6);
      #pragma unroll
      for (int m = 0; m < 16; ++m) {
        float4 h4 = *(const float4*)(hp + 4 * m);
        pwh += whv[m].x * h4.x + whv[m].y * h4.y + whv[m].z * h4.z + whv[m].w * h4.w;
      }
    }
    // ---- poll all 512 psi elements (one per thread) ----
    {
      const unsigned long long* p = psiX + ((unsigned)(st & 1) * 16u + b) * 512u + t;
      unsigned long long v = gloadU64(p);
      while ((unsigned)(v >> 32) < (unsigned)(st + 1)) v = gloadU64(p);
      psiA[t] = __uint_as_float((unsigned)v);
    }
    __syncthreads();
    // ---- Si assembly + mask + softmax (wave 0) ----
    if (t < 64) {
      float acc = 0.f;
      #pragma unroll
      for (int w = 0; w < 8; ++w) acc += psiA[(w << 6) + t];
      float v = mL[t] ? acc : NEGV;
      float mx = v;
      #pragma unroll
      for (int d = 1; d < 64; d <<= 1) mx = fmaxf(mx, __shfl_xor(mx, d));
      float e = __expf(v - mx);
      float ssum = e;
      #pragma unroll
      for (int d = 1; d < 64; d <<= 1) ssum += __shfl_xor(ssum, d);
      attL[t] = e / ssum;
    }
    __syncthreads();
    // ---- g[rl] = Xx + pwh + att@SWM (quarter dots, reduce over q) ----
    {
      float p = pwh;
      const float* sb = swmB + q * 2560 + rl * 20;
      const float* atb = attL + (q << 4);
      #pragma unroll
      for (int i2 = 0; i2 < 4; ++i2) {
        float4 s4 = *(const float4*)(sb + 4 * i2);
        float4 a4 = *(const float4*)(atb + 4 * i2);
        p += s4.x * a4.x + s4.y * a4.y + s4.z * a4.z + s4.w * a4.w;
      }
      p += __shfl_xor(p, 1); p += __shfl_xor(p, 2);
      if (q == 0) gA[rl] = p + xx_r;
    }
    __syncthreads();
    // ---- gates + publish h (tag|value) ----
    if (t < 32) {
      float gi = gA[t], gf = gA[32 + t], gg = gA[64 + t], go = gA[96 + t];
      c_reg = sigf(gf) * c_reg + sigf(gi) * tanhfast(gg);
      float hn = sigf(go) * tanhfast(c_reg);
      unsigned long long pv = ((unsigned long long)(unsigned)(st + 1) << 32)
                            | (unsigned long long)__float_as_uint(hn);
      gstoreU64(hx + (unsigned)((st + 1) & 1) * 4096u + b * 256 + (j << 5) + t, pv);
    }
  }

  // ---- final classifier (WG j==0 per batch) ----
  if (j == 0) {
    float v = 0.f;
    if (t < 256) {
      const unsigned long long* p = hx + 0 * 4096u + b * 256 + t;  // slot 64&1==0
      unsigned long long vv = gloadU64(p);
      while ((unsigned)(vv >> 32) < 64u) vv = gloadU64(p);
      v = __uint_as_float((unsigned)vv) * fc_w[t];
    }
    #pragma unroll
    for (int d = 1; d < 64; d <<= 1) v += __shfl_xor(v, d);
    if (t < 256 && (t & 63) == 0) redL[t >> 6] = v;
    __syncthreads();
    if (t == 0) out[b] = sigf(redL[0] + redL[1] + redL[2] + redL[3] + fc_b[0]);
  }
}

extern "C" void kernel_launch(void* const* d_in, const int* in_sizes, int n_in,
                              void* d_out, int out_size, void* d_ws, size_t ws_size,
                              hipStream_t stream) {
  const int*   x      = (const int*)d_in[0];
  const int*   mask   = (const int*)d_in[1];
  const float* embed  = (const float*)d_in[3];
  const float* W_ih   = (const float*)d_in[4];
  const float* W_hh   = (const float*)d_in[5];
  const float* b_ih   = (const float*)d_in[6];
  const float* b_hh   = (const float*)d_in[7];
  const float* Ws_w   = (const float*)d_in[8];
  const float* Ws_b   = (const float*)d_in[9];
  const float* Us_w   = (const float*)d_in[10];
  const float* Wx     = (const float*)d_in[12];
  const float* Wh     = (const float*)d_in[13];
  const float* Wm     = (const float*)d_in[14];
  const float* b_cell = (const float*)d_in[15];
  const float* fc_w   = (const float*)d_in[16];
  const float* fc_b   = (const float*)d_in[17];
  float* ws  = (float*)d_ws;
  float* out = (float*)d_out;

  k1_precompute<<<dim3(1152), dim3(256), 0, stream>>>(
      x, embed, W_ih, b_ih, b_hh, Ws_w, Ws_b, Wx, b_cell, ws);
  k2_shared_lstm<<<dim3(128), dim3(512), 0, stream>>>(W_hh, ws);
  k3_precompute2<<<dim3(640), dim3(256), 0, stream>>>(Ws_w, Wm, ws);
  k4_task_lstm<<<dim3(128), dim3(512), 0, stream>>>(
      mask, Ws_w, Us_w, Wh, fc_w, fc_b, ws, out);
}